// Round 2
// baseline (674.433 us; speedup 1.0000x reference)
//
#include <hip/hip_runtime.h>
#include <cstdint>

#define TOK 16384
#define HD 2048
#define NE 64
#define HQ 512
#define KSPLIT 4
#define KSL (HD / KSPLIT)   // 512
#define KCH 32
#define LSCALE 33554432.0f          // 2^25
#define LINV (1.0f / 33554432.0f)
#define ESCALE 1073741824.0f        // 2^30

// ---------------------------------------------------------------------------
// K1: router logits (fixed-point int32 partial accumulation) + fused colsum.
// Block: 256 thr = 4 waves; 64 tokens x 64 experts x 512 K per block.
// lane = token; wave = 16 experts; B read as wave-uniform global float4
// (single L2 request, broadcast); A staged in LDS stride-33 (conflict-free).
// Grid: 256 token-groups x 4 k-slices = 1024 blocks = 4/CU -> 16 waves/CU.
// ---------------------------------------------------------------------------
__global__ __launch_bounds__(256, 4) void k_router(const float* __restrict__ hid,
                                                   const float* __restrict__ rw,
                                                   int* __restrict__ lacc,
                                                   float* __restrict__ colsum) {
  __shared__ float As[64][33];
  __shared__ float red[8][32];
  const int tid = threadIdx.x;
  const int lane = tid & 63;
  const int wv = tid >> 6;
  const int tg = blockIdx.x >> 2;
  const int ks = blockIdx.x & 3;
  const int t0 = tg * 64;
  const int k0 = ks * KSL;
  const int srow = tid >> 2;
  const int scol = (tid & 3) * 8;
  const float* hrow = hid + (size_t)(t0 + srow) * HD + k0 + scol;
  const float* bbase = rw + (size_t)(wv * 16) * HD + k0;

  float acc[16];
#pragma unroll
  for (int e = 0; e < 16; ++e) acc[e] = 0.f;

  float4 a0 = *(const float4*)(hrow);
  float4 a1 = *(const float4*)(hrow + 4);

  for (int kc = 0; kc < KSL; kc += KCH) {
    __syncthreads();
    // flush previous chunk's column-sum partials (red stable until next write)
    if (kc > 0 && tid < 32) {
      float s = red[0][tid] + red[1][tid] + red[2][tid] + red[3][tid] +
                red[4][tid] + red[5][tid] + red[6][tid] + red[7][tid];
      atomicAdd(&colsum[k0 + kc - KCH + tid], s);
    }
    As[srow][scol + 0] = a0.x; As[srow][scol + 1] = a0.y;
    As[srow][scol + 2] = a0.z; As[srow][scol + 3] = a0.w;
    As[srow][scol + 4] = a1.x; As[srow][scol + 5] = a1.y;
    As[srow][scol + 6] = a1.z; As[srow][scol + 7] = a1.w;
    __syncthreads();
    // column partial sums for this chunk (per-wave 2-way bank alias: free)
    {
      const int col = tid & 31, grp = tid >> 5;
      float s = 0.f;
#pragma unroll
      for (int i = 0; i < 8; ++i) s += As[grp * 8 + i][col];
      red[grp][col] = s;
    }
    // prefetch next A chunk (hides HBM latency under compute)
    if (kc + KCH < KSL) {
      a0 = *(const float4*)(hrow + kc + KCH);
      a1 = *(const float4*)(hrow + kc + KCH + 4);
    }
    const float* bc = bbase + kc;
#pragma unroll
    for (int kq = 0; kq < KCH; kq += 4) {
      const float av0 = As[lane][kq + 0];
      const float av1 = As[lane][kq + 1];
      const float av2 = As[lane][kq + 2];
      const float av3 = As[lane][kq + 3];
#pragma unroll
      for (int h = 0; h < 2; ++h) {
        float4 b[8];
#pragma unroll
        for (int j = 0; j < 8; ++j)
          b[j] = *(const float4*)(bc + (size_t)(h * 8 + j) * HD + kq);
#pragma unroll
        for (int j = 0; j < 8; ++j) {
          acc[h * 8 + j] += av0 * b[j].x;
          acc[h * 8 + j] += av1 * b[j].y;
          acc[h * 8 + j] += av2 * b[j].z;
          acc[h * 8 + j] += av3 * b[j].w;
        }
      }
    }
  }
  __syncthreads();
  if (tid < 32) {
    float s = red[0][tid] + red[1][tid] + red[2][tid] + red[3][tid] +
              red[4][tid] + red[5][tid] + red[6][tid] + red[7][tid];
    atomicAdd(&colsum[k0 + KSL - KCH + tid], s);
  }
  // deterministic k-slice reduction: integer atomics are associative
  int* la = lacc + (size_t)(t0 + lane) * NE + wv * 16;
#pragma unroll
  for (int e = 0; e < 16; ++e)
    atomicAdd(&la[e], __float2int_rn(acc[e] * LSCALE));
}

// ---------------------------------------------------------------------------
// K2a: h = relu(cap_w1 @ mean_h + b1), one block per output row.
// ---------------------------------------------------------------------------
__global__ __launch_bounds__(256) void k_cap1(const float* __restrict__ w1,
                                              const float* __restrict__ b1,
                                              const float* __restrict__ colsum,
                                              float* __restrict__ h) {
  const int row = blockIdx.x;
  const int tid = threadIdx.x;
  const float invB = 1.0f / 16384.0f;
  const float* wr = w1 + (size_t)row * HD;
  float4 a0 = *(const float4*)(wr + tid * 4);
  float4 a1 = *(const float4*)(wr + 1024 + tid * 4);
  float4 c0 = *(const float4*)(colsum + tid * 4);
  float4 c1 = *(const float4*)(colsum + 1024 + tid * 4);
  float s = a0.x * (c0.x * invB) + a0.y * (c0.y * invB) +
            a0.z * (c0.z * invB) + a0.w * (c0.w * invB) +
            a1.x * (c1.x * invB) + a1.y * (c1.y * invB) +
            a1.z * (c1.z * invB) + a1.w * (c1.w * invB);
#pragma unroll
  for (int off = 32; off; off >>= 1) s += __shfl_down(s, off);
  __shared__ float wsum[4];
  if ((tid & 63) == 0) wsum[tid >> 6] = s;
  __syncthreads();
  if (tid == 0) {
    float t = wsum[0] + wsum[1] + wsum[2] + wsum[3] + b1[row];
    h[row] = fmaxf(t, 0.f);
  }
}

// ---------------------------------------------------------------------------
// K2b: cap_logits = cap_w2 @ h + b2, one block per expert.
// ---------------------------------------------------------------------------
__global__ __launch_bounds__(128) void k_cap2(const float* __restrict__ w2,
                                              const float* __restrict__ b2,
                                              const float* __restrict__ h,
                                              float* __restrict__ cl) {
  const int e = blockIdx.x, tid = threadIdx.x;
  float4 a = *(const float4*)(w2 + (size_t)e * HQ + tid * 4);
  float4 hv = *(const float4*)(h + tid * 4);
  float s = a.x * hv.x + a.y * hv.y + a.z * hv.z + a.w * hv.w;
#pragma unroll
  for (int off = 32; off; off >>= 1) s += __shfl_down(s, off);
  __shared__ float wsum[2];
  if ((tid & 63) == 0) wsum[tid >> 6] = s;
  __syncthreads();
  if (tid == 0) cl[e] = wsum[0] + wsum[1] + b2[e];
}

// ---------------------------------------------------------------------------
// K2c: softmax(cap_logits) -> clip -> capacity, one wave.
// ---------------------------------------------------------------------------
__global__ __launch_bounds__(64) void k_capacity(const float* __restrict__ cl,
                                                 int* __restrict__ cap) {
  const int tid = threadIdx.x;
  float l = cl[tid];
  float m = l;
#pragma unroll
  for (int off = 1; off < 64; off <<= 1) m = fmaxf(m, __shfl_xor(m, off));
  float ex = expf(l - m);
  float s = ex;
#pragma unroll
  for (int off = 1; off < 64; off <<= 1) s += __shfl_xor(s, off);
  float w = ex / s;
  float cf = 1.25f + (w - 0.5f) * 1.0f;
  cf = fminf(fmaxf(cf, 1.0f), 2.0f);
  cap[tid] = (int)floorf(16384.0f * cf / 64.0f);
}

// ---------------------------------------------------------------------------
// K3a: convert int32 logits -> f32 (in place, to d_out), per-token softmax,
// write probsT [E][B], entropy (deterministic int64 fixed-point atomic).
// ---------------------------------------------------------------------------
__global__ __launch_bounds__(256) void k_softmax(int* __restrict__ lacc,
                                                 float* __restrict__ probsT,
                                                 unsigned long long* __restrict__ ent) {
  __shared__ float tp[64][65];
  __shared__ float sw[4];
  const int tid = threadIdx.x;
  const int lane = tid & 63;
  const int wv = tid >> 6;
  const int t0 = blockIdx.x * 64;
  const int tl = tid >> 2, q = tid & 3;
  const int t = t0 + tl;
  int* lr = lacc + (size_t)t * NE + q * 16;
  int4 i0 = *(const int4*)(lr);
  int4 i1 = *(const int4*)(lr + 4);
  int4 i2 = *(const int4*)(lr + 8);
  int4 i3 = *(const int4*)(lr + 12);
  float p[16] = {i0.x * LINV, i0.y * LINV, i0.z * LINV, i0.w * LINV,
                 i1.x * LINV, i1.y * LINV, i1.z * LINV, i1.w * LINV,
                 i2.x * LINV, i2.y * LINV, i2.z * LINV, i2.w * LINV,
                 i3.x * LINV, i3.y * LINV, i3.z * LINV, i3.w * LINV};
  // write f32 logits over the int buffer (same addresses, same thread)
  float* lw = (float*)lr;
  *(float4*)(lw)      = make_float4(p[0], p[1], p[2], p[3]);
  *(float4*)(lw + 4)  = make_float4(p[4], p[5], p[6], p[7]);
  *(float4*)(lw + 8)  = make_float4(p[8], p[9], p[10], p[11]);
  *(float4*)(lw + 12) = make_float4(p[12], p[13], p[14], p[15]);
  float m = p[0];
#pragma unroll
  for (int i = 1; i < 16; ++i) m = fmaxf(m, p[i]);
  m = fmaxf(m, __shfl_xor(m, 1));
  m = fmaxf(m, __shfl_xor(m, 2));
  float s = 0.f;
#pragma unroll
  for (int i = 0; i < 16; ++i) { p[i] = expf(p[i] - m); s += p[i]; }
  s += __shfl_xor(s, 1);
  s += __shfl_xor(s, 2);
  const float inv = 1.0f / s;
  float el = 0.f;
#pragma unroll
  for (int i = 0; i < 16; ++i) {
    float pp = p[i] * inv;
    p[i] = pp;
    el += pp * logf(pp + 1e-8f);
  }
  el += __shfl_xor(el, 1);
  el += __shfl_xor(el, 2);
  float ew = (q == 0) ? el : 0.f;
#pragma unroll
  for (int off = 4; off < 64; off <<= 1) ew += __shfl_xor(ew, off);
  if (lane == 0) sw[wv] = ew;
#pragma unroll
  for (int i = 0; i < 16; ++i) tp[q * 16 + i][tl] = p[i];
  __syncthreads();
  if (tid == 0) {
    float bt = sw[0] + sw[1] + sw[2] + sw[3];
    atomicAdd(ent, (unsigned long long)(long long)__float2ll_rn(bt * ESCALE));
  }
  const int er = tid >> 6, tl2 = tid & 63;
#pragma unroll
  for (int pass = 0; pass < 16; ++pass) {
    const int e = pass * 4 + er;
    probsT[(size_t)e * TOK + t0 + tl2] = tp[e][tl2];
  }
}

// ---------------------------------------------------------------------------
// K3b: per-expert exact k-th largest prob via radix select; ballot match-any
// histogram (no same-address LDS atomic storms) + parallel suffix scan.
// ---------------------------------------------------------------------------
__global__ __launch_bounds__(256) void k_selthr(const float* __restrict__ probsT,
                                                const int* __restrict__ cap,
                                                unsigned* __restrict__ thrT,
                                                int* __restrict__ cutoff) {
  const int e = blockIdx.x, tid = threadIdx.x;
  const int lane = tid & 63;
  const unsigned* col = (const unsigned*)(probsT + (size_t)e * TOK);
  __shared__ int hist[256];
  __shared__ unsigned sh_pref;
  __shared__ int sh_rem;
  __shared__ int sred[4];
  __shared__ int sgt[4], seq2[4];
  const int k = cap[e];
  unsigned prefix = 0, pmask = 0;
  int rem = k;
  for (int pass = 0; pass < 4; ++pass) {
    const int shift = 24 - 8 * pass;
    hist[tid] = 0;
    __syncthreads();
    for (int i = tid; i < TOK; i += 256) {
      const unsigned v = col[i];
      const bool ok = (v & pmask) == prefix;
      const unsigned b = (v >> shift) & 255u;
      const unsigned key = ok ? b : 256u;
      unsigned long long mm = ~0ULL;
#pragma unroll
      for (int bit = 0; bit < 9; ++bit) {
        const unsigned long long bb = __ballot((key >> bit) & 1u);
        mm &= ((key >> bit) & 1u) ? bb : ~bb;
      }
      const int leader = __ffsll((unsigned long long)mm) - 1;
      if (key < 256u && lane == leader) atomicAdd(&hist[b], (int)__popcll(mm));
    }
    __syncthreads();
    // in-place parallel suffix scan over 256 buckets
    for (int off = 1; off < 256; off <<= 1) {
      const int add = (tid + off < 256) ? hist[tid + off] : 0;
      __syncthreads();
      hist[tid] += add;
      __syncthreads();
    }
    const int sb = hist[tid];
    const int sn = (tid < 255) ? hist[tid + 1] : 0;
    if (sb >= rem && sn < rem) {  // unique bucket
      sh_pref = prefix | ((unsigned)tid << shift);
      sh_rem = rem - sn;
    }
    __syncthreads();
    prefix = sh_pref;
    rem = sh_rem;
    pmask |= 255u << shift;
    __syncthreads();
  }
  const unsigned T = prefix;
  int lgt = 0, leq = 0;
  for (int i = tid; i < TOK; i += 256) {
    const unsigned v = col[i];
    lgt += (v > T);
    leq += (v == T);
  }
#pragma unroll
  for (int off = 32; off; off >>= 1) {
    lgt += __shfl_down(lgt, off);
    leq += __shfl_down(leq, off);
  }
  if ((tid & 63) == 0) { sgt[tid >> 6] = lgt; seq2[tid >> 6] = leq; }
  __syncthreads();
  const int c_gt = sgt[0] + sgt[1] + sgt[2] + sgt[3];
  const int c_eq = seq2[0] + seq2[1] + seq2[2] + seq2[3];
  const int n_allowed = k - c_gt;
  int cut;
  if (n_allowed <= 0) {
    cut = -1;
  } else if (c_eq <= n_allowed) {
    cut = 0x7fffffff;
  } else {
    int lo = 0, hi = TOK - 1;
    while (lo < hi) {
      const int mid = (lo + hi) >> 1;
      int c = 0;
      for (int i = tid; i <= mid; i += 256) c += (col[i] == T);
#pragma unroll
      for (int off = 32; off; off >>= 1) c += __shfl_down(c, off);
      __syncthreads();
      if ((tid & 63) == 0) sred[tid >> 6] = c;
      __syncthreads();
      const int cnt = sred[0] + sred[1] + sred[2] + sred[3];
      if (cnt >= n_allowed) hi = mid; else lo = mid + 1;
    }
    cut = lo;
  }
  if (tid == 0) { thrT[e] = T; cutoff[e] = cut; }
}

// ---------------------------------------------------------------------------
// K3c: per-token selection + weight + entropy finalize.
// ---------------------------------------------------------------------------
__global__ __launch_bounds__(256) void k_final(const float* __restrict__ probsT,
                                               const unsigned* __restrict__ thrT,
                                               const int* __restrict__ cutoff,
                                               const unsigned long long* __restrict__ ent,
                                               float* __restrict__ out_sel,
                                               float* __restrict__ out_w,
                                               float* __restrict__ out_ent) {
  __shared__ float tp[64][65];
  __shared__ unsigned sT[64];
  __shared__ int sC[64];
  const int tid = threadIdx.x;
  const int t0 = blockIdx.x * 64;
  if (tid < 64) { sT[tid] = thrT[tid]; sC[tid] = cutoff[tid]; }
  const int er = tid >> 6, tl2 = tid & 63;
#pragma unroll
  for (int pass = 0; pass < 16; ++pass) {
    const int e = pass * 4 + er;
    tp[e][tl2] = probsT[(size_t)e * TOK + t0 + tl2];
  }
  __syncthreads();
  const int tl = tid >> 2, q = tid & 3;
  const int t_abs = t0 + tl;
  int best = -1;
  float bw = 0.f;
  for (int i = 15; i >= 0; --i) {
    const int e = q * 16 + i;
    const float p = tp[e][tl];
    const unsigned v = __float_as_uint(p);
    const unsigned T = sT[e];
    if (v > T || (v == T && t_abs <= sC[e])) { best = e; bw = p; break; }
  }
#pragma unroll
  for (int off = 1; off <= 2; off <<= 1) {
    const int b2 = __shfl_xor(best, off);
    const float w2 = __shfl_xor(bw, off);
    if (b2 > best) { best = b2; bw = w2; }
  }
  if (q == 0) {
    out_sel[t_abs] = (float)(best >= 0 ? best : 0);
    out_w[t_abs] = (best >= 0 ? bw : 0.0f);
  }
  if (blockIdx.x == 0 && tid == 0)
    out_ent[0] = -((float)(long long)ent[0] * (1.0f / ESCALE)) / 16384.0f;
}

// ---------------------------------------------------------------------------
extern "C" void kernel_launch(void* const* d_in, const int* in_sizes, int n_in,
                              void* d_out, int out_size, void* d_ws, size_t ws_size,
                              hipStream_t stream) {
  const float* hid = (const float*)d_in[0];
  const float* rw  = (const float*)d_in[1];
  const float* w1  = (const float*)d_in[2];
  const float* b1  = (const float*)d_in[3];
  const float* w2  = (const float*)d_in[4];
  const float* b2  = (const float*)d_in[5];
  float* out = (float*)d_out;
  float* logits  = out;                       // [TOK][NE] (int32 acc, then f32)
  float* out_sel = out + (size_t)TOK * NE;
  float* out_w   = out_sel + TOK;
  float* out_ent = out_w + TOK;
  char* ws = (char*)d_ws;
  float*              colsum = (float*)(ws + 0);        // 2048 f32
  unsigned long long* ent    = (unsigned long long*)(ws + 8192);
  float*              h      = (float*)(ws + 8448);     // 512 f32
  float*              cl     = (float*)(ws + 10496);    // 64 f32
  int*                cap    = (int*)(ws + 10752);      // 64 i32
  unsigned*           thr    = (unsigned*)(ws + 11008); // 64 u32
  int*                cut    = (int*)(ws + 11264);      // 64 i32
  float*              probsT = (float*)(ws + 16384);    // 4 MiB

  hipMemsetAsync(d_ws, 0, 16384, stream);                       // colsum + ent
  hipMemsetAsync(d_out, 0, (size_t)TOK * NE * sizeof(int), stream);  // logit acc
  hipLaunchKernelGGL(k_router, dim3(TOK / 64 * KSPLIT), dim3(256), 0, stream,
                     hid, rw, (int*)logits, colsum);
  hipLaunchKernelGGL(k_cap1, dim3(HQ), dim3(256), 0, stream, w1, b1, colsum, h);
  hipLaunchKernelGGL(k_cap2, dim3(NE), dim3(128), 0, stream, w2, b2, h, cl);
  hipLaunchKernelGGL(k_capacity, dim3(1), dim3(64), 0, stream, cl, cap);
  hipLaunchKernelGGL(k_softmax, dim3(TOK / 64), dim3(256), 0, stream,
                     (int*)logits, probsT, ent);
  hipLaunchKernelGGL(k_selthr, dim3(NE), dim3(256), 0, stream, probsT, cap, thr, cut);
  hipLaunchKernelGGL(k_final, dim3(TOK / 64), dim3(256), 0, stream,
                     probsT, thr, cut, ent, out_sel, out_w, out_ent);
}

// Round 3
// 314.428 us; speedup vs baseline: 2.1450x; 2.1450x over previous
//
#include <hip/hip_runtime.h>
#include <cstdint>

#define TOK 16384
#define HD 2048
#define NE 64
#define HQ 512
#define KSPLIT 2
#define KSL (HD / KSPLIT)      // 1024 k per block
#define KC 32                  // k chunk
#define NCH (KSL / KC)         // 32 chunks
#define ESCALE 1073741824.0f   // 2^30

// ---------------------------------------------------------------------------
// K1: router logits partials P[ks][e][t] (plain stores, no atomics) + block-
// local colsum -> csP partial buffer. 512 thr = 8 waves; block = 64 tok x
// 64 exp x 1024 k. Grid 512 = 2 blocks/CU = 4 waves/SIMD. A rows stride-33
// (conflict-free b32 per-lane reads), B rows stride-32 (wave-uniform b128
// broadcast reads). Double-buffered, one barrier per chunk.
// ---------------------------------------------------------------------------
__global__ __launch_bounds__(512, 4) void k_router(const float* __restrict__ hid,
                                                   const float* __restrict__ rw,
                                                   float* __restrict__ P,
                                                   float* __restrict__ csP) {
  __shared__ float As[2][64][33];
  __shared__ float Bs[2][64][32];
  __shared__ float cs[KSL];
  const int tid = threadIdx.x;
  const int lane = tid & 63;
  const int w = tid >> 6;              // wave 0..7 -> experts w*8..w*8+7
  const int tg = blockIdx.x >> 1;
  const int ks = blockIdx.x & 1;
  const int t0 = tg * 64;
  const int k0 = ks * KSL;
  cs[tid] = 0.f;
  cs[tid + 512] = 0.f;
  const int st = tid >> 3;             // token (A) / expert (B) 0..63
  const int sk = (tid & 7) * 4;        // k offset within chunk
  const float* ha = hid + (size_t)(t0 + st) * HD + k0 + sk;
  const float* ba = rw + (size_t)st * HD + k0 + sk;
  float4 a4 = *(const float4*)(ha);
  float4 b4 = *(const float4*)(ba);
  float acc[8];
#pragma unroll
  for (int e = 0; e < 8; ++e) acc[e] = 0.f;
  const int e0 = w * 8;

  for (int c = 0; c < NCH; ++c) {
    const int cur = c & 1;
    As[cur][st][sk + 0] = a4.x; As[cur][st][sk + 1] = a4.y;
    As[cur][st][sk + 2] = a4.z; As[cur][st][sk + 3] = a4.w;
    *(float4*)&Bs[cur][st][sk] = b4;
    if (c + 1 < NCH) {
      a4 = *(const float4*)(ha + (c + 1) * KC);
      b4 = *(const float4*)(ba + (c + 1) * KC);
    }
    __syncthreads();
    // block-local colsum for this chunk (LDS f32 atomic; feeds capacity only,
    // which clips to exactly 256 with huge margin -> order-safe)
    {
      const int ko = tid & 31, g4 = tid >> 5;  // 16 groups of 4 tokens
      float s = As[cur][g4 * 4 + 0][ko] + As[cur][g4 * 4 + 1][ko] +
                As[cur][g4 * 4 + 2][ko] + As[cur][g4 * 4 + 3][ko];
      atomicAdd(&cs[c * KC + ko], s);
    }
    // compute: lane = token, 8 experts per wave
    float vA[KC];
#pragma unroll
    for (int k = 0; k < KC; ++k) vA[k] = As[cur][lane][k];
#pragma unroll
    for (int e = 0; e < 8; ++e) {
      const float* br = &Bs[cur][e0 + e][0];
#pragma unroll
      for (int q = 0; q < KC; q += 4) {
        float4 b = *(const float4*)(br + q);
        acc[e] = fmaf(vA[q + 0], b.x, acc[e]);
        acc[e] = fmaf(vA[q + 1], b.y, acc[e]);
        acc[e] = fmaf(vA[q + 2], b.z, acc[e]);
        acc[e] = fmaf(vA[q + 3], b.w, acc[e]);
      }
    }
  }
  __syncthreads();
  // partial logits, [ks][e][t] layout -> fully coalesced 64-lane stores
  float* Pp = P + (size_t)ks * NE * TOK;
#pragma unroll
  for (int e = 0; e < 8; ++e)
    Pp[(size_t)(e0 + e) * TOK + t0 + lane] = acc[e];
  // colsum partial (no atomics; reduced deterministically by k_reduce_cs)
  csP[(size_t)blockIdx.x * KSL + tid] = cs[tid];
  csP[(size_t)blockIdx.x * KSL + 512 + tid] = cs[tid + 512];
}

// ---------------------------------------------------------------------------
// K1b: colsum[k] = sum over the 256 token-group blocks (fixed order).
// ---------------------------------------------------------------------------
__global__ __launch_bounds__(256) void k_reduce_cs(const float* __restrict__ csP,
                                                   float* __restrict__ colsum) {
  const int k = blockIdx.x * 256 + threadIdx.x;  // 0..2047
  const int ks = k >> 10, ko = k & 1023;
  float s = 0.f;
  for (int tg = 0; tg < 256; ++tg)
    s += csP[(size_t)(tg * 2 + ks) * KSL + ko];
  colsum[k] = s;
}

// ---------------------------------------------------------------------------
// K2a: h = relu(cap_w1 @ mean_h + b1), one block per output row.
// ---------------------------------------------------------------------------
__global__ __launch_bounds__(256) void k_cap1(const float* __restrict__ w1,
                                              const float* __restrict__ b1,
                                              const float* __restrict__ colsum,
                                              float* __restrict__ h) {
  const int row = blockIdx.x;
  const int tid = threadIdx.x;
  const float invB = 1.0f / 16384.0f;
  const float* wr = w1 + (size_t)row * HD;
  float4 a0 = *(const float4*)(wr + tid * 4);
  float4 a1 = *(const float4*)(wr + 1024 + tid * 4);
  float4 c0 = *(const float4*)(colsum + tid * 4);
  float4 c1 = *(const float4*)(colsum + 1024 + tid * 4);
  float s = a0.x * (c0.x * invB) + a0.y * (c0.y * invB) +
            a0.z * (c0.z * invB) + a0.w * (c0.w * invB) +
            a1.x * (c1.x * invB) + a1.y * (c1.y * invB) +
            a1.z * (c1.z * invB) + a1.w * (c1.w * invB);
#pragma unroll
  for (int off = 32; off; off >>= 1) s += __shfl_down(s, off);
  __shared__ float wsum[4];
  if ((tid & 63) == 0) wsum[tid >> 6] = s;
  __syncthreads();
  if (tid == 0) {
    float t = wsum[0] + wsum[1] + wsum[2] + wsum[3] + b1[row];
    h[row] = fmaxf(t, 0.f);
  }
}

// ---------------------------------------------------------------------------
// K2b: cap_logits = cap_w2 @ h + b2, one block per expert.
// ---------------------------------------------------------------------------
__global__ __launch_bounds__(128) void k_cap2(const float* __restrict__ w2,
                                              const float* __restrict__ b2,
                                              const float* __restrict__ h,
                                              float* __restrict__ cl) {
  const int e = blockIdx.x, tid = threadIdx.x;
  float4 a = *(const float4*)(w2 + (size_t)e * HQ + tid * 4);
  float4 hv = *(const float4*)(h + tid * 4);
  float s = a.x * hv.x + a.y * hv.y + a.z * hv.z + a.w * hv.w;
#pragma unroll
  for (int off = 32; off; off >>= 1) s += __shfl_down(s, off);
  __shared__ float wsum[2];
  if ((tid & 63) == 0) wsum[tid >> 6] = s;
  __syncthreads();
  if (tid == 0) cl[e] = wsum[0] + wsum[1] + b2[e];
}

// ---------------------------------------------------------------------------
// K2c: softmax(cap_logits) -> clip -> capacity, one wave.
// ---------------------------------------------------------------------------
__global__ __launch_bounds__(64) void k_capacity(const float* __restrict__ cl,
                                                 int* __restrict__ cap) {
  const int tid = threadIdx.x;
  float l = cl[tid];
  float m = l;
#pragma unroll
  for (int off = 1; off < 64; off <<= 1) m = fmaxf(m, __shfl_xor(m, off));
  float ex = expf(l - m);
  float s = ex;
#pragma unroll
  for (int off = 1; off < 64; off <<= 1) s += __shfl_xor(s, off);
  float w = ex / s;
  float cf = 1.25f + (w - 0.5f) * 1.0f;
  cf = fminf(fmaxf(cf, 1.0f), 2.0f);
  cap[tid] = (int)floorf(16384.0f * cf / 64.0f);
}

// ---------------------------------------------------------------------------
// K3a: logits = P0+P1 (deterministic), per-token softmax, write logits [t][e]
// + probsT [e][t] (overlays P1: same layout, block-local read-then-write),
// entropy via int64 fixed-point atomic (deterministic).
// ---------------------------------------------------------------------------
__global__ __launch_bounds__(256) void k_softmax(const float* __restrict__ P,
                                                 float* __restrict__ logits,
                                                 float* __restrict__ probsT,
                                                 unsigned long long* __restrict__ ent) {
  __shared__ float tp[64][65];
  __shared__ float sw[4];
  const int tid = threadIdx.x;
  const int t0 = blockIdx.x * 64;
  const int er = tid >> 6, tl = tid & 63;
  const float* P0 = P;
  const float* P1 = P + (size_t)NE * TOK;
#pragma unroll
  for (int pass = 0; pass < 16; ++pass) {
    const int e = pass * 4 + er;
    tp[tl][e] = P0[(size_t)e * TOK + t0 + tl] + P1[(size_t)e * TOK + t0 + tl];
  }
  __syncthreads();
  const int tt = tid >> 2, q = tid & 3;
  float l[16], p[16];
#pragma unroll
  for (int i = 0; i < 16; ++i) l[i] = tp[tt][q * 16 + i];
  float m = l[0];
#pragma unroll
  for (int i = 1; i < 16; ++i) m = fmaxf(m, l[i]);
  m = fmaxf(m, __shfl_xor(m, 1));
  m = fmaxf(m, __shfl_xor(m, 2));
  float s = 0.f;
#pragma unroll
  for (int i = 0; i < 16; ++i) { p[i] = expf(l[i] - m); s += p[i]; }
  s += __shfl_xor(s, 1);
  s += __shfl_xor(s, 2);
  const float inv = 1.0f / s;
  float el = 0.f;
#pragma unroll
  for (int i = 0; i < 16; ++i) {
    float pp = p[i] * inv;
    p[i] = pp;
    el += pp * logf(pp + 1e-8f);
  }
  el += __shfl_xor(el, 1);
  el += __shfl_xor(el, 2);
  // logits [t][e], 4x b128 per thread, coalesced
  float* lrow = logits + (size_t)(t0 + tt) * NE + q * 16;
  *(float4*)(lrow + 0)  = make_float4(l[0], l[1], l[2], l[3]);
  *(float4*)(lrow + 4)  = make_float4(l[4], l[5], l[6], l[7]);
  *(float4*)(lrow + 8)  = make_float4(l[8], l[9], l[10], l[11]);
  *(float4*)(lrow + 12) = make_float4(l[12], l[13], l[14], l[15]);
  // probsT [e][t] (overlay on P1; this block's token range only)
#pragma unroll
  for (int i = 0; i < 16; ++i)
    probsT[(size_t)(q * 16 + i) * TOK + t0 + tt] = p[i];
  // entropy: one contribution per token (q==0), wave+block reduce, int64 atomic
  float ew = (q == 0) ? el : 0.f;
#pragma unroll
  for (int off = 4; off < 64; off <<= 1) ew += __shfl_xor(ew, off);
  if ((tid & 63) == 0) sw[tid >> 6] = ew;
  __syncthreads();
  if (tid == 0) {
    float bt = sw[0] + sw[1] + sw[2] + sw[3];
    atomicAdd(ent, (unsigned long long)(long long)__float2ll_rn(bt * ESCALE));
  }
}

// ---------------------------------------------------------------------------
// K3b: per-expert exact k-th largest prob via radix select (ballot match-any
// histogram + parallel suffix scan) + stable-sort tie cutoff.
// ---------------------------------------------------------------------------
__global__ __launch_bounds__(256) void k_selthr(const float* __restrict__ probsT,
                                                const int* __restrict__ cap,
                                                unsigned* __restrict__ thrT,
                                                int* __restrict__ cutoff) {
  const int e = blockIdx.x, tid = threadIdx.x;
  const int lane = tid & 63;
  const unsigned* col = (const unsigned*)(probsT + (size_t)e * TOK);
  __shared__ int hist[256];
  __shared__ unsigned sh_pref;
  __shared__ int sh_rem;
  __shared__ int sred[4];
  __shared__ int sgt[4], seq2[4];
  const int k = cap[e];
  unsigned prefix = 0, pmask = 0;
  int rem = k;
  for (int pass = 0; pass < 4; ++pass) {
    const int shift = 24 - 8 * pass;
    hist[tid] = 0;
    __syncthreads();
    for (int i = tid; i < TOK; i += 256) {
      const unsigned v = col[i];
      const bool ok = (v & pmask) == prefix;
      const unsigned b = (v >> shift) & 255u;
      const unsigned key = ok ? b : 256u;
      unsigned long long mm = ~0ULL;
#pragma unroll
      for (int bit = 0; bit < 9; ++bit) {
        const unsigned long long bb = __ballot((key >> bit) & 1u);
        mm &= ((key >> bit) & 1u) ? bb : ~bb;
      }
      const int leader = __ffsll((unsigned long long)mm) - 1;
      if (key < 256u && lane == leader) atomicAdd(&hist[b], (int)__popcll(mm));
    }
    __syncthreads();
    for (int off = 1; off < 256; off <<= 1) {
      const int add = (tid + off < 256) ? hist[tid + off] : 0;
      __syncthreads();
      hist[tid] += add;
      __syncthreads();
    }
    const int sb = hist[tid];
    const int sn = (tid < 255) ? hist[tid + 1] : 0;
    if (sb >= rem && sn < rem) {
      sh_pref = prefix | ((unsigned)tid << shift);
      sh_rem = rem - sn;
    }
    __syncthreads();
    prefix = sh_pref;
    rem = sh_rem;
    pmask |= 255u << shift;
    __syncthreads();
  }
  const unsigned T = prefix;
  int lgt = 0, leq = 0;
  for (int i = tid; i < TOK; i += 256) {
    const unsigned v = col[i];
    lgt += (v > T);
    leq += (v == T);
  }
#pragma unroll
  for (int off = 32; off; off >>= 1) {
    lgt += __shfl_down(lgt, off);
    leq += __shfl_down(leq, off);
  }
  if ((tid & 63) == 0) { sgt[tid >> 6] = lgt; seq2[tid >> 6] = leq; }
  __syncthreads();
  const int c_gt = sgt[0] + sgt[1] + sgt[2] + sgt[3];
  const int c_eq = seq2[0] + seq2[1] + seq2[2] + seq2[3];
  const int n_allowed = k - c_gt;
  int cut;
  if (n_allowed <= 0) {
    cut = -1;
  } else if (c_eq <= n_allowed) {
    cut = 0x7fffffff;
  } else {
    int lo = 0, hi = TOK - 1;
    while (lo < hi) {
      const int mid = (lo + hi) >> 1;
      int c = 0;
      for (int i = tid; i <= mid; i += 256) c += (col[i] == T);
#pragma unroll
      for (int off = 32; off; off >>= 1) c += __shfl_down(c, off);
      __syncthreads();
      if ((tid & 63) == 0) sred[tid >> 6] = c;
      __syncthreads();
      const int cnt = sred[0] + sred[1] + sred[2] + sred[3];
      if (cnt >= n_allowed) hi = mid; else lo = mid + 1;
    }
    cut = lo;
  }
  if (tid == 0) { thrT[e] = T; cutoff[e] = cut; }
}

// ---------------------------------------------------------------------------
// K3c: per-token selection + weight + entropy finalize.
// ---------------------------------------------------------------------------
__global__ __launch_bounds__(256) void k_final(const float* __restrict__ probsT,
                                               const unsigned* __restrict__ thrT,
                                               const int* __restrict__ cutoff,
                                               const unsigned long long* __restrict__ ent,
                                               float* __restrict__ out_sel,
                                               float* __restrict__ out_w,
                                               float* __restrict__ out_ent) {
  __shared__ float tp[64][65];
  __shared__ unsigned sT[64];
  __shared__ int sC[64];
  const int tid = threadIdx.x;
  const int t0 = blockIdx.x * 64;
  if (tid < 64) { sT[tid] = thrT[tid]; sC[tid] = cutoff[tid]; }
  const int er = tid >> 6, tl2 = tid & 63;
#pragma unroll
  for (int pass = 0; pass < 16; ++pass) {
    const int e = pass * 4 + er;
    tp[e][tl2] = probsT[(size_t)e * TOK + t0 + tl2];
  }
  __syncthreads();
  const int tl = tid >> 2, q = tid & 3;
  const int t_abs = t0 + tl;
  int best = -1;
  float bw = 0.f;
  for (int i = 15; i >= 0; --i) {
    const int e = q * 16 + i;
    const float p = tp[e][tl];
    const unsigned v = __float_as_uint(p);
    const unsigned T = sT[e];
    if (v > T || (v == T && t_abs <= sC[e])) { best = e; bw = p; break; }
  }
#pragma unroll
  for (int off = 1; off <= 2; off <<= 1) {
    const int b2 = __shfl_xor(best, off);
    const float w2 = __shfl_xor(bw, off);
    if (b2 > best) { best = b2; bw = w2; }
  }
  if (q == 0) {
    out_sel[t_abs] = (float)(best >= 0 ? best : 0);
    out_w[t_abs] = (best >= 0 ? bw : 0.0f);
  }
  if (blockIdx.x == 0 && tid == 0)
    out_ent[0] = -((float)(long long)ent[0] * (1.0f / ESCALE)) / 16384.0f;
}

// ---------------------------------------------------------------------------
extern "C" void kernel_launch(void* const* d_in, const int* in_sizes, int n_in,
                              void* d_out, int out_size, void* d_ws, size_t ws_size,
                              hipStream_t stream) {
  const float* hid = (const float*)d_in[0];
  const float* rw  = (const float*)d_in[1];
  const float* w1  = (const float*)d_in[2];
  const float* b1  = (const float*)d_in[3];
  const float* w2  = (const float*)d_in[4];
  const float* b2  = (const float*)d_in[5];
  float* out = (float*)d_out;
  float* logits  = out;
  float* out_sel = out + (size_t)TOK * NE;
  float* out_w   = out_sel + TOK;
  float* out_ent = out_w + TOK;
  char* ws = (char*)d_ws;
  float*              colsum = (float*)(ws + 0);        // 2048 f32
  unsigned long long* ent    = (unsigned long long*)(ws + 8192);
  float*              h      = (float*)(ws + 8448);     // 512 f32
  float*              cl     = (float*)(ws + 10496);    // 64 f32
  int*                cap    = (int*)(ws + 10752);
  unsigned*           thr    = (unsigned*)(ws + 11008);
  int*                cut    = (int*)(ws + 11264);
  float*              csP    = (float*)(ws + 16384);               // 2 MiB
  float*              P      = (float*)(ws + 16384 + (size_t)512 * KSL * 4);  // 8 MiB
  float*              probsT = P + (size_t)NE * TOK;    // overlays P1

  hipMemsetAsync(ent, 0, 8, stream);
  hipLaunchKernelGGL(k_router, dim3(512), dim3(512), 0, stream, hid, rw, P, csP);
  hipLaunchKernelGGL(k_reduce_cs, dim3(8), dim3(256), 0, stream, csP, colsum);
  hipLaunchKernelGGL(k_cap1, dim3(HQ), dim3(256), 0, stream, w1, b1, colsum, h);
  hipLaunchKernelGGL(k_cap2, dim3(NE), dim3(128), 0, stream, w2, b2, h, cl);
  hipLaunchKernelGGL(k_capacity, dim3(1), dim3(64), 0, stream, cl, cap);
  hipLaunchKernelGGL(k_softmax, dim3(TOK / 64), dim3(256), 0, stream,
                     P, logits, probsT, ent);
  hipLaunchKernelGGL(k_selthr, dim3(NE), dim3(256), 0, stream, probsT, cap, thr, cut);
  hipLaunchKernelGGL(k_final, dim3(TOK / 64), dim3(256), 0, stream,
                     probsT, thr, cut, ent, out_sel, out_w, out_ent);
}

// Round 4
// 152.173 us; speedup vs baseline: 4.4320x; 2.0663x over previous
//
#include <hip/hip_runtime.h>
#include <cstdint>

#define TOK 16384
#define HD 2048
#define NE 64
#define HQ 512
#define KC 64
#define NCH (HD / KC)          // 32 chunks
#define ESCALE 1073741824.0f   // 2^30

// ---------------------------------------------------------------------------
// K1: router logits = hid @ rw^T (f32, full K per block) + fused colsum
// partials. 256 thr = 4 waves; block tile 32 tok x 64 exp x 2048 k.
// Wave tile 16x32, thread tile 2 tok x 4 exp (6 LDS reads : 32 FMA per quad).
// Grid 512 = 2 blocks/CU = 2 waves/SIMD. XOR-swizzled LDS (32B granularity):
// A pair^(row&7) (rows differ in tm = low bits), B pair^((row>>2)&7) (rows
// differ in tn at bit 2+) -> all compute reads bank-conflict-free.
// Logits written directly to d_out [t][e], fully coalesced float4.
// ---------------------------------------------------------------------------
__global__ __launch_bounds__(256, 2) void k_router(const float* __restrict__ hid,
                                                   const float* __restrict__ rw,
                                                   float* __restrict__ logits,
                                                   float* __restrict__ csP) {
  __shared__ __align__(16) float As[2][32][KC];
  __shared__ __align__(16) float Bs[2][64][KC];
  __shared__ float red[2][4][64];
  const int tid = threadIdx.x;
  const int lane = tid & 63;
  const int w = tid >> 6;
  const int tm = lane >> 3, tn = lane & 7;
  const int tsub = w >> 1, ehalf = w & 1;
  const int t0 = blockIdx.x * 32;
  // staging: A: 32 rows x 64 f = 8KB -> 8 floats/thread (one 2-quad pair)
  //          B: 64 rows x 64 f = 16KB -> 16 floats/thread (two pairs)
  const int arow = tid >> 3;
  const int apr = tid & 7;              // A pair index
  const int brow = tid >> 2;
  const int bpr = (tid & 3) * 2;        // B first pair
  const float* hap = hid + (size_t)(t0 + arow) * HD + apr * 8;
  const float* bap = rw + (size_t)brow * HD + (tid & 3) * 16;
  const int aswz = arow & 7;
  const int bswz = (brow >> 2) & 7;
  const int aoff = ((apr ^ aswz) << 3);
  const int boff0 = (((bpr + 0) ^ bswz) << 3);
  const int boff1 = (((bpr + 1) ^ bswz) << 3);

  float4 va0 = *(const float4*)(hap);
  float4 va1 = *(const float4*)(hap + 4);
  float4 vb0 = *(const float4*)(bap);
  float4 vb1 = *(const float4*)(bap + 4);
  float4 vb2 = *(const float4*)(bap + 8);
  float4 vb3 = *(const float4*)(bap + 12);

  float acc[2][4];
#pragma unroll
  for (int i = 0; i < 2; ++i)
#pragma unroll
    for (int j = 0; j < 4; ++j) acc[i][j] = 0.f;

  const int rA0 = tsub * 16 + tm;       // +8 for second token
  const int rB0 = ehalf * 32 + tn * 4;  // 4 consecutive expert rows

  for (int c = 0; c < NCH; ++c) {
    const int cur = c & 1;
    *(float4*)&As[cur][arow][aoff] = va0;
    *(float4*)&As[cur][arow][aoff + 4] = va1;
    *(float4*)&Bs[cur][brow][boff0] = vb0;
    *(float4*)&Bs[cur][brow][boff0 + 4] = vb1;
    *(float4*)&Bs[cur][brow][boff1] = vb2;
    *(float4*)&Bs[cur][brow][boff1 + 4] = vb3;
    if (c + 1 < NCH) {
      va0 = *(const float4*)(hap + (c + 1) * KC);
      va1 = *(const float4*)(hap + (c + 1) * KC + 4);
      vb0 = *(const float4*)(bap + (c + 1) * KC);
      vb1 = *(const float4*)(bap + (c + 1) * KC + 4);
      vb2 = *(const float4*)(bap + (c + 1) * KC + 8);
      vb3 = *(const float4*)(bap + (c + 1) * KC + 12);
    }
    __syncthreads();
    // flush previous chunk's colsum partial (deterministic, no atomics)
    if (c > 0 && tid < 64) {
      const int pb = cur ^ 1;
      float v = red[pb][0][tid] + red[pb][1][tid] + red[pb][2][tid] + red[pb][3][tid];
      csP[(size_t)blockIdx.x * HD + (c - 1) * KC + tid] = v;
    }
    // this chunk's colsum partial: wave g sums rows g*8..g*8+7
    {
      const int col = tid & 63, grp = tid >> 6;
      float s = 0.f;
#pragma unroll
      for (int i = 0; i < 8; ++i) {
        const int row = grp * 8 + i;
        s += As[cur][row][(((col >> 3) ^ (row & 7)) << 3) + (col & 7)];
      }
      red[cur][grp][col] = s;
    }
    // compute: 8 quad-pairs x (12 ds_read_b128 + 64 FMA)
#pragma unroll
    for (int qp = 0; qp < 8; ++qp) {
      const int oa = ((qp ^ tm) << 3);
      const int ob = ((qp ^ tn) << 3);
#pragma unroll
      for (int h = 0; h < 2; ++h) {
        float4 a0 = *(const float4*)&As[cur][rA0][oa + h * 4];
        float4 a1 = *(const float4*)&As[cur][rA0 + 8][oa + h * 4];
        float4 b0 = *(const float4*)&Bs[cur][rB0 + 0][ob + h * 4];
        float4 b1 = *(const float4*)&Bs[cur][rB0 + 1][ob + h * 4];
        float4 b2 = *(const float4*)&Bs[cur][rB0 + 2][ob + h * 4];
        float4 b3 = *(const float4*)&Bs[cur][rB0 + 3][ob + h * 4];
        acc[0][0] = fmaf(a0.x, b0.x, acc[0][0]);
        acc[0][0] = fmaf(a0.y, b0.y, acc[0][0]);
        acc[0][0] = fmaf(a0.z, b0.z, acc[0][0]);
        acc[0][0] = fmaf(a0.w, b0.w, acc[0][0]);
        acc[0][1] = fmaf(a0.x, b1.x, acc[0][1]);
        acc[0][1] = fmaf(a0.y, b1.y, acc[0][1]);
        acc[0][1] = fmaf(a0.z, b1.z, acc[0][1]);
        acc[0][1] = fmaf(a0.w, b1.w, acc[0][1]);
        acc[0][2] = fmaf(a0.x, b2.x, acc[0][2]);
        acc[0][2] = fmaf(a0.y, b2.y, acc[0][2]);
        acc[0][2] = fmaf(a0.z, b2.z, acc[0][2]);
        acc[0][2] = fmaf(a0.w, b2.w, acc[0][2]);
        acc[0][3] = fmaf(a0.x, b3.x, acc[0][3]);
        acc[0][3] = fmaf(a0.y, b3.y, acc[0][3]);
        acc[0][3] = fmaf(a0.z, b3.z, acc[0][3]);
        acc[0][3] = fmaf(a0.w, b3.w, acc[0][3]);
        acc[1][0] = fmaf(a1.x, b0.x, acc[1][0]);
        acc[1][0] = fmaf(a1.y, b0.y, acc[1][0]);
        acc[1][0] = fmaf(a1.z, b0.z, acc[1][0]);
        acc[1][0] = fmaf(a1.w, b0.w, acc[1][0]);
        acc[1][1] = fmaf(a1.x, b1.x, acc[1][1]);
        acc[1][1] = fmaf(a1.y, b1.y, acc[1][1]);
        acc[1][1] = fmaf(a1.z, b1.z, acc[1][1]);
        acc[1][1] = fmaf(a1.w, b1.w, acc[1][1]);
        acc[1][2] = fmaf(a1.x, b2.x, acc[1][2]);
        acc[1][2] = fmaf(a1.y, b2.y, acc[1][2]);
        acc[1][2] = fmaf(a1.z, b2.z, acc[1][2]);
        acc[1][2] = fmaf(a1.w, b2.w, acc[1][2]);
        acc[1][3] = fmaf(a1.x, b3.x, acc[1][3]);
        acc[1][3] = fmaf(a1.y, b3.y, acc[1][3]);
        acc[1][3] = fmaf(a1.z, b3.z, acc[1][3]);
        acc[1][3] = fmaf(a1.w, b3.w, acc[1][3]);
      }
    }
  }
  __syncthreads();
  // final colsum flush (chunk 31 -> red buffer 1)
  if (tid < 64) {
    float v = red[1][0][tid] + red[1][1][tid] + red[1][2][tid] + red[1][3][tid];
    csP[(size_t)blockIdx.x * HD + (NCH - 1) * KC + tid] = v;
  }
  // logits [t][e], float4, fully coalesced (8 lanes -> 128B line)
  const int tA = t0 + tsub * 16 + tm;
  const int eA = ehalf * 32 + tn * 4;
  *(float4*)&logits[(size_t)tA * NE + eA] = make_float4(acc[0][0], acc[0][1], acc[0][2], acc[0][3]);
  *(float4*)&logits[(size_t)(tA + 8) * NE + eA] = make_float4(acc[1][0], acc[1][1], acc[1][2], acc[1][3]);
}

// ---------------------------------------------------------------------------
// K1b: colsum[k] = sum over 512 blocks (fixed order, deterministic).
// ---------------------------------------------------------------------------
__global__ __launch_bounds__(256) void k_reduce_cs(const float* __restrict__ csP,
                                                   float* __restrict__ colsum) {
  __shared__ float rr[4][64];
  const int tid = threadIdx.x;
  const int k = blockIdx.x * 64 + (tid & 63);
  const int part = tid >> 6;
  float s = 0.f;
  for (int b = part * 128; b < part * 128 + 128; ++b)
    s += csP[(size_t)b * HD + k];
  rr[part][tid & 63] = s;
  __syncthreads();
  if (tid < 64)
    colsum[blockIdx.x * 64 + tid] = rr[0][tid] + rr[1][tid] + rr[2][tid] + rr[3][tid];
}

// ---------------------------------------------------------------------------
// K2a: h = relu(cap_w1 @ mean_h + b1), one block per output row.
// ---------------------------------------------------------------------------
__global__ __launch_bounds__(256) void k_cap1(const float* __restrict__ w1,
                                              const float* __restrict__ b1,
                                              const float* __restrict__ colsum,
                                              float* __restrict__ h) {
  const int row = blockIdx.x;
  const int tid = threadIdx.x;
  const float invB = 1.0f / 16384.0f;
  const float* wr = w1 + (size_t)row * HD;
  float4 a0 = *(const float4*)(wr + tid * 4);
  float4 a1 = *(const float4*)(wr + 1024 + tid * 4);
  float4 c0 = *(const float4*)(colsum + tid * 4);
  float4 c1 = *(const float4*)(colsum + 1024 + tid * 4);
  float s = a0.x * (c0.x * invB) + a0.y * (c0.y * invB) +
            a0.z * (c0.z * invB) + a0.w * (c0.w * invB) +
            a1.x * (c1.x * invB) + a1.y * (c1.y * invB) +
            a1.z * (c1.z * invB) + a1.w * (c1.w * invB);
#pragma unroll
  for (int off = 32; off; off >>= 1) s += __shfl_down(s, off);
  __shared__ float wsum[4];
  if ((tid & 63) == 0) wsum[tid >> 6] = s;
  __syncthreads();
  if (tid == 0) {
    float t = wsum[0] + wsum[1] + wsum[2] + wsum[3] + b1[row];
    h[row] = fmaxf(t, 0.f);
  }
}

// ---------------------------------------------------------------------------
// K2b: cap_logits = cap_w2 @ h + b2, one block per expert.
// ---------------------------------------------------------------------------
__global__ __launch_bounds__(128) void k_cap2(const float* __restrict__ w2,
                                              const float* __restrict__ b2,
                                              const float* __restrict__ h,
                                              float* __restrict__ cl) {
  const int e = blockIdx.x, tid = threadIdx.x;
  float4 a = *(const float4*)(w2 + (size_t)e * HQ + tid * 4);
  float4 hv = *(const float4*)(h + tid * 4);
  float s = a.x * hv.x + a.y * hv.y + a.z * hv.z + a.w * hv.w;
#pragma unroll
  for (int off = 32; off; off >>= 1) s += __shfl_down(s, off);
  __shared__ float wsum[2];
  if ((tid & 63) == 0) wsum[tid >> 6] = s;
  __syncthreads();
  if (tid == 0) cl[e] = wsum[0] + wsum[1] + b2[e];
}

// ---------------------------------------------------------------------------
// K2c: softmax(cap_logits) -> clip -> capacity, one wave.
// ---------------------------------------------------------------------------
__global__ __launch_bounds__(64) void k_capacity(const float* __restrict__ cl,
                                                 int* __restrict__ cap) {
  const int tid = threadIdx.x;
  float l = cl[tid];
  float m = l;
#pragma unroll
  for (int off = 1; off < 64; off <<= 1) m = fmaxf(m, __shfl_xor(m, off));
  float ex = expf(l - m);
  float s = ex;
#pragma unroll
  for (int off = 1; off < 64; off <<= 1) s += __shfl_xor(s, off);
  float w = ex / s;
  float cf = 1.25f + (w - 0.5f) * 1.0f;
  cf = fminf(fmaxf(cf, 1.0f), 2.0f);
  cap[tid] = (int)floorf(16384.0f * cf / 64.0f);
}

// ---------------------------------------------------------------------------
// K3a: per-token softmax (reads logits [t][e] from d_out), writes probsT
// [e][t] via LDS transpose; entropy via int64 fixed-point atomic.
// ---------------------------------------------------------------------------
__global__ __launch_bounds__(256) void k_softmax(const float* __restrict__ logits,
                                                 float* __restrict__ probsT,
                                                 unsigned long long* __restrict__ ent) {
  __shared__ float tpT[64][65];
  __shared__ float sw[4];
  const int tid = threadIdx.x;
  const int lane = tid & 63;
  const int wv = tid >> 6;
  const int t0 = blockIdx.x * 64;
  const int tt = tid >> 2, q = tid & 3;
  const float* lr = logits + (size_t)(t0 + tt) * NE + q * 16;
  float4 v0 = *(const float4*)(lr);
  float4 v1 = *(const float4*)(lr + 4);
  float4 v2 = *(const float4*)(lr + 8);
  float4 v3 = *(const float4*)(lr + 12);
  float p[16] = {v0.x, v0.y, v0.z, v0.w, v1.x, v1.y, v1.z, v1.w,
                 v2.x, v2.y, v2.z, v2.w, v3.x, v3.y, v3.z, v3.w};
  float m = p[0];
#pragma unroll
  for (int i = 1; i < 16; ++i) m = fmaxf(m, p[i]);
  m = fmaxf(m, __shfl_xor(m, 1));
  m = fmaxf(m, __shfl_xor(m, 2));
  float s = 0.f;
#pragma unroll
  for (int i = 0; i < 16; ++i) { p[i] = expf(p[i] - m); s += p[i]; }
  s += __shfl_xor(s, 1);
  s += __shfl_xor(s, 2);
  const float inv = 1.0f / s;
  float el = 0.f;
#pragma unroll
  for (int i = 0; i < 16; ++i) {
    float pp = p[i] * inv;
    p[i] = pp;
    el += pp * logf(pp + 1e-8f);
  }
  el += __shfl_xor(el, 1);
  el += __shfl_xor(el, 2);
#pragma unroll
  for (int i = 0; i < 16; ++i) tpT[q * 16 + i][tt] = p[i];
  float ew = (q == 0) ? el : 0.f;
#pragma unroll
  for (int off = 4; off < 64; off <<= 1) ew += __shfl_xor(ew, off);
  if (lane == 0) sw[wv] = ew;
  __syncthreads();
  if (tid == 0) {
    float bt = sw[0] + sw[1] + sw[2] + sw[3];
    atomicAdd(ent, (unsigned long long)(long long)__float2ll_rn(bt * ESCALE));
  }
  const int er = tid >> 6, tl = tid & 63;
#pragma unroll
  for (int pass = 0; pass < 16; ++pass) {
    const int e = pass * 4 + er;
    probsT[(size_t)e * TOK + t0 + tl] = tpT[e][tl];
  }
}

// ---------------------------------------------------------------------------
// K3b: per-expert exact k-th largest prob: 3-pass radix select (11/11/10
// bits, 2048-bin LDS histogram, uint4 loads, parallel suffix scan) +
// stable-sort tie cutoff. One block per expert.
// ---------------------------------------------------------------------------
__global__ __launch_bounds__(256) void k_selthr(const float* __restrict__ probsT,
                                                const int* __restrict__ cap,
                                                unsigned* __restrict__ thrT,
                                                int* __restrict__ cutoff) {
  const int e = blockIdx.x, tid = threadIdx.x;
  const uint4* col4 = (const uint4*)(probsT + (size_t)e * TOK);
  const unsigned* col = (const unsigned*)(probsT + (size_t)e * TOK);
  __shared__ unsigned hist[2048];
  __shared__ int wsfx[256];
  __shared__ unsigned sh_pref;
  __shared__ int sh_rem;
  __shared__ int sred[4], sgt[4], seq2[4];
  const int k = cap[e];
  unsigned prefix = 0, pmask = 0;
  int rem = k;
#pragma unroll
  for (int pass = 0; pass < 3; ++pass) {
    const int shift = (pass == 0) ? 21 : (pass == 1) ? 10 : 0;
    const int nb = (pass == 2) ? 1024 : 2048;
    const unsigned bmask = nb - 1;
    for (int i = tid; i < nb; i += 256) hist[i] = 0;
    __syncthreads();
    for (int it = 0; it < TOK / 1024; ++it) {
      uint4 v = col4[it * 256 + tid];
      if ((v.x & pmask) == prefix) atomicAdd(&hist[(v.x >> shift) & bmask], 1u);
      if ((v.y & pmask) == prefix) atomicAdd(&hist[(v.y >> shift) & bmask], 1u);
      if ((v.z & pmask) == prefix) atomicAdd(&hist[(v.z >> shift) & bmask], 1u);
      if ((v.w & pmask) == prefix) atomicAdd(&hist[(v.w >> shift) & bmask], 1u);
    }
    __syncthreads();
    const int cs = nb >> 8;  // 8 or 4 bins per thread
    const int base = tid * cs;
    int s = 0;
    for (int m2 = 0; m2 < cs; ++m2) s += (int)hist[base + m2];
    wsfx[tid] = s;
    __syncthreads();
    for (int off = 1; off < 256; off <<= 1) {
      int v = (tid + off < 256) ? wsfx[tid + off] : 0;
      __syncthreads();
      wsfx[tid] += v;
      __syncthreads();
    }
    int r = (tid < 255) ? wsfx[tid + 1] : 0;
    for (int m2 = cs - 1; m2 >= 0; --m2) {
      int rb = r + (int)hist[base + m2];
      if (rb >= rem && r < rem) {
        sh_pref = prefix | ((unsigned)(base + m2) << shift);
        sh_rem = rem - r;
      }
      r = rb;
    }
    __syncthreads();
    prefix = sh_pref;
    rem = sh_rem;
    pmask |= bmask << shift;
    __syncthreads();
  }
  const unsigned T = prefix;
  int lgt = 0, leq = 0;
  for (int it = 0; it < TOK / 1024; ++it) {
    uint4 v = col4[it * 256 + tid];
    lgt += (v.x > T) + (v.y > T) + (v.z > T) + (v.w > T);
    leq += (v.x == T) + (v.y == T) + (v.z == T) + (v.w == T);
  }
#pragma unroll
  for (int off = 32; off; off >>= 1) {
    lgt += __shfl_down(lgt, off);
    leq += __shfl_down(leq, off);
  }
  if ((tid & 63) == 0) { sgt[tid >> 6] = lgt; seq2[tid >> 6] = leq; }
  __syncthreads();
  const int c_gt = sgt[0] + sgt[1] + sgt[2] + sgt[3];
  const int c_eq = seq2[0] + seq2[1] + seq2[2] + seq2[3];
  const int n_allowed = k - c_gt;
  int cut;
  if (n_allowed <= 0) {
    cut = -1;
  } else if (c_eq <= n_allowed) {
    cut = 0x7fffffff;
  } else {
    int lo = 0, hi = TOK - 1;
    while (lo < hi) {
      const int mid = (lo + hi) >> 1;
      int c = 0;
      for (int i = tid; i <= mid; i += 256) c += (col[i] == T);
#pragma unroll
      for (int off = 32; off; off >>= 1) c += __shfl_down(c, off);
      __syncthreads();
      if ((tid & 63) == 0) sred[tid >> 6] = c;
      __syncthreads();
      const int cnt = sred[0] + sred[1] + sred[2] + sred[3];
      if (cnt >= n_allowed) hi = mid; else lo = mid + 1;
    }
    cut = lo;
  }
  if (tid == 0) { thrT[e] = T; cutoff[e] = cut; }
}

// ---------------------------------------------------------------------------
// K3c: per-token selection + weight + entropy finalize.
// ---------------------------------------------------------------------------
__global__ __launch_bounds__(256) void k_final(const float* __restrict__ probsT,
                                               const unsigned* __restrict__ thrT,
                                               const int* __restrict__ cutoff,
                                               const unsigned long long* __restrict__ ent,
                                               float* __restrict__ out_sel,
                                               float* __restrict__ out_w,
                                               float* __restrict__ out_ent) {
  __shared__ float tp[64][65];
  __shared__ unsigned sT[64];
  __shared__ int sC[64];
  const int tid = threadIdx.x;
  const int t0 = blockIdx.x * 64;
  if (tid < 64) { sT[tid] = thrT[tid]; sC[tid] = cutoff[tid]; }
  const int er = tid >> 6, tl2 = tid & 63;
#pragma unroll
  for (int pass = 0; pass < 16; ++pass) {
    const int e = pass * 4 + er;
    tp[e][tl2] = probsT[(size_t)e * TOK + t0 + tl2];
  }
  __syncthreads();
  const int tl = tid >> 2, q = tid & 3;
  const int t_abs = t0 + tl;
  int best = -1;
  float bw = 0.f;
  for (int i = 15; i >= 0; --i) {
    const int e = q * 16 + i;
    const float p = tp[e][tl];
    const unsigned v = __float_as_uint(p);
    const unsigned T = sT[e];
    if (v > T || (v == T && t_abs <= sC[e])) { best = e; bw = p; break; }
  }
#pragma unroll
  for (int off = 1; off <= 2; off <<= 1) {
    const int b2 = __shfl_xor(best, off);
    const float w2 = __shfl_xor(bw, off);
    if (b2 > best) { best = b2; bw = w2; }
  }
  if (q == 0) {
    out_sel[t_abs] = (float)(best >= 0 ? best : 0);
    out_w[t_abs] = (best >= 0 ? bw : 0.0f);
  }
  if (blockIdx.x == 0 && tid == 0)
    out_ent[0] = -((float)(long long)ent[0] * (1.0f / ESCALE)) / 16384.0f;
}

// ---------------------------------------------------------------------------
extern "C" void kernel_launch(void* const* d_in, const int* in_sizes, int n_in,
                              void* d_out, int out_size, void* d_ws, size_t ws_size,
                              hipStream_t stream) {
  (void)in_sizes; (void)n_in; (void)out_size; (void)ws_size;
  const float* hid = (const float*)d_in[0];
  const float* rw  = (const float*)d_in[1];
  const float* w1  = (const float*)d_in[2];
  const float* b1  = (const float*)d_in[3];
  const float* w2  = (const float*)d_in[4];
  const float* b2  = (const float*)d_in[5];
  float* out = (float*)d_out;
  float* logits  = out;
  float* out_sel = out + (size_t)TOK * NE;
  float* out_w   = out_sel + TOK;
  float* out_ent = out_w + TOK;
  char* ws = (char*)d_ws;
  float*              colsum = (float*)(ws + 0);        // 2048 f32
  unsigned long long* ent    = (unsigned long long*)(ws + 8192);
  float*              h      = (float*)(ws + 8448);     // 512 f32
  float*              cl     = (float*)(ws + 10496);    // 64 f32
  int*                cap    = (int*)(ws + 10752);
  unsigned*           thr    = (unsigned*)(ws + 11008);
  int*                cut    = (int*)(ws + 11264);
  float*              csP    = (float*)(ws + 16384);                   // 4 MiB
  float*              probsT = (float*)(ws + 16384 + (size_t)512 * HD * 4);  // 4 MiB

  hipMemsetAsync(ent, 0, 8, stream);
  hipLaunchKernelGGL(k_router, dim3(TOK / 32), dim3(256), 0, stream, hid, rw, logits, csP);
  hipLaunchKernelGGL(k_reduce_cs, dim3(HD / 64), dim3(256), 0, stream, csP, colsum);
  hipLaunchKernelGGL(k_cap1, dim3(HQ), dim3(256), 0, stream, w1, b1, colsum, h);
  hipLaunchKernelGGL(k_cap2, dim3(NE), dim3(128), 0, stream, w2, b2, h, cl);
  hipLaunchKernelGGL(k_capacity, dim3(1), dim3(64), 0, stream, cl, cap);
  hipLaunchKernelGGL(k_softmax, dim3(TOK / 64), dim3(256), 0, stream, logits, probsT, ent);
  hipLaunchKernelGGL(k_selthr, dim3(NE), dim3(256), 0, stream, probsT, cap, thr, cut);
  hipLaunchKernelGGL(k_final, dim3(TOK / 64), dim3(256), 0, stream,
                     probsT, thr, cut, ent, out_sel, out_w, out_ent);
}